// Round 1
// 733.108 us; speedup vs baseline: 1.1097x; 1.1097x over previous
//
#include <hip/hip_runtime.h>

// Problem constants
#define NFR   128      // N frames
#define PP    576      // patches
#define DD    1536     // dim
#define LMM   4096
#define NQQ   64
#define PQ    9        // P / NQ
#define NCUBES 8
#define NSEL  9        // 1 forced + 8 cubes
#define D4    384      // DD / 4 (float4 columns)

// ---------------- ws layout (float offsets), total ~13.4 MB ----------------
// Region A (0 .. 1,572,864) is time-shared: part -> Cpart(DxD,8 splits) -> Cpart(thumb,4 splits)
#define OFF_A      0u
#define OFF_VFMEAN 1572864u      // (unused after k2 fusion; kept for layout stability)
#define OFF_MOM    1769472u      // [128][1536]  momMean (row 127 zeroed)
#define OFF_XN     1966080u      // [128][1536]
#define OFF_H      2162688u      // (unused after k5b fusion)
#define OFF_PPART  2359296u      // [9][64][1536] pooled partials
#define OFF_POOLED 3244032u      // [64][1536]
#define OFF_Y      3342336u      // [127]
#define OFF_SEL    3342464u      // [9] ints

// Output layout (fp32): gate_logits [127,2] @0, thumbnail [64,4096] @254, z_hard [128] @262398
#define OUT_GATE  0
#define OUT_THUMB 254
#define OUT_Z     262398

// ---------------- K1: per-frame patch-sum partials ----------------
// grid (128 frames, 8 p-chunks), 384 threads; each thread one float4 column.
__global__ __launch_bounds__(384) void k1_partial(const float* __restrict__ vf,
                                                  float* __restrict__ part) {
    const int n  = blockIdx.x;
    const int ps = blockIdx.y;
    const int c4 = threadIdx.x;
    const float4* v = (const float4*)vf;
    float4 acc = make_float4(0.f, 0.f, 0.f, 0.f);
    int base = (n * PP + ps * 72) * D4 + c4;
#pragma unroll 8
    for (int p = 0; p < 72; ++p) {
        float4 x = v[base + p * D4];
        acc.x += x.x; acc.y += x.y; acc.z += x.z; acc.w += x.w;
    }
    ((float4*)part)[(n * 8 + ps) * D4 + c4] = acc;
}

// ---------------- K2 (fused k2a+k2b): partials -> mean -> EMA scan -> momMean ----------------
// Same arithmetic order as the previous two kernels (ps-ascending sum, *1/576, then scan).
__device__ __forceinline__ float frameMean(const float* __restrict__ part, int n, int d) {
    float s = 0.f;
#pragma unroll
    for (int ps = 0; ps < 8; ++ps) s += part[(n * 8 + ps) * DD + d];
    return s * (1.0f / 576.0f);
}

__global__ __launch_bounds__(64) void k2_scan(const float* __restrict__ part,
                                              float* __restrict__ momMean) {
    const int d = blockIdx.x * 64 + threadIdx.x;   // 24 blocks x 64 = 1536 columns
    float prev = frameMean(part, 0, d);
    float cur  = frameMean(part, 1, d);
    float ema  = cur - prev;        // delta_1 = d_1
    momMean[d] = ema;
    prev = cur;
#pragma unroll 4
    for (int n = 2; n < NFR; ++n) {
        cur = frameMean(part, n, d);
        float diff = cur - prev;
        ema = 0.5f * diff + 0.5f * ema;   // ALPHA = 0.5
        momMean[(n - 1) * DD + d] = ema;
        prev = cur;
    }
    momMean[127 * DD + d] = 0.f;    // pad row for M=128 GEMM
}

// ---------------- split-K fp32 GEMM: Cpart[s] = A[:,ks] @ B[ks,:] ----------------
// Deterministic (no atomics). grid (N/64, M/64, splits), 256 threads.
// Software-pipelined: next K-step's global loads issue before the FMA inner loop,
// so HBM/L2 latency hides under the ~512-cycle compute.
#define GKC 16
__global__ __launch_bounds__(256) void gemm_sk(const float* __restrict__ A,
                                               const float* __restrict__ B,
                                               float* __restrict__ Cpart,
                                               int M, int N, int K, int kChunk) {
    const int j0 = blockIdx.x * 64;
    const int i0 = blockIdx.y * 64;
    const int s  = blockIdx.z;
    const int k0 = s * kChunk;
    __shared__ float As[GKC][68];   // [k][i], padded
    __shared__ float Bs[GKC][68];   // [k][j], padded
    const int tid = threadIdx.x;
    const int tx = tid & 15, ty = tid >> 4;
    const int ai = tid >> 2, ak4 = (tid & 3) * 4;   // A: row ai, k-offset ak4
    const int bk = tid >> 4, bj4 = (tid & 15) * 4;  // B: k-row bk, j-offset bj4
    float c[4][4] = {};
    const float* Ap = A + (size_t)(i0 + ai) * K + ak4;
    const float* Bp = B + (size_t)bk * N + j0 + bj4;
    float4 av = *(const float4*)(Ap + k0);
    float4 bv = *(const float4*)(Bp + (size_t)k0 * N);
    for (int kk = k0; kk < k0 + kChunk; kk += GKC) {
        __syncthreads();
        As[ak4 + 0][ai] = av.x; As[ak4 + 1][ai] = av.y;
        As[ak4 + 2][ai] = av.z; As[ak4 + 3][ai] = av.w;
        Bs[bk][bj4 + 0] = bv.x; Bs[bk][bj4 + 1] = bv.y;
        Bs[bk][bj4 + 2] = bv.z; Bs[bk][bj4 + 3] = bv.w;
        __syncthreads();
        if (kk + GKC < k0 + kChunk) {   // uniform branch: prefetch next K-step
            av = *(const float4*)(Ap + kk + GKC);
            bv = *(const float4*)(Bp + (size_t)(kk + GKC) * N);
        }
#pragma unroll
        for (int k = 0; k < GKC; ++k) {
            float a0 = As[k][ty * 4 + 0], a1 = As[k][ty * 4 + 1];
            float a2 = As[k][ty * 4 + 2], a3 = As[k][ty * 4 + 3];
            float b0 = Bs[k][tx * 4 + 0], b1 = Bs[k][tx * 4 + 1];
            float b2 = Bs[k][tx * 4 + 2], b3 = Bs[k][tx * 4 + 3];
            c[0][0] += a0 * b0; c[0][1] += a0 * b1; c[0][2] += a0 * b2; c[0][3] += a0 * b3;
            c[1][0] += a1 * b0; c[1][1] += a1 * b1; c[1][2] += a1 * b2; c[1][3] += a1 * b3;
            c[2][0] += a2 * b0; c[2][1] += a2 * b1; c[2][2] += a2 * b2; c[2][3] += a2 * b3;
            c[3][0] += a3 * b0; c[3][1] += a3 * b1; c[3][2] += a3 * b2; c[3][3] += a3 * b3;
        }
    }
    float* Cp = Cpart + (size_t)s * M * N;
#pragma unroll
    for (int ii = 0; ii < 4; ++ii)
#pragma unroll
        for (int jj = 0; jj < 4; ++jj)
            Cp[(size_t)(i0 + ty * 4 + ii) * N + j0 + tx * 4 + jj] = c[ii][jj];
}

// ---------------- block reduce (blockDim = 256) ----------------
__device__ __forceinline__ float blockSum(float v, float* sb) {
#pragma unroll
    for (int o = 32; o > 0; o >>= 1) v += __shfl_down(v, o);
    __syncthreads();
    if ((threadIdx.x & 63) == 0) sb[threadIdx.x >> 6] = v;
    __syncthreads();
    return sb[0] + sb[1] + sb[2] + sb[3];
}

// ---------------- K4: reduce split-K partials + b_agg, LayerNorm -> xn ----------------
__global__ __launch_bounds__(256) void k4_ln(const float* __restrict__ Cpart,
                                             const float* __restrict__ b_agg,
                                             const float* __restrict__ ln_g,
                                             const float* __restrict__ ln_b,
                                             float* __restrict__ xn) {
    __shared__ float sb[4];
    const int n = blockIdx.x;
    if (n == 127) {   // pad row: keep defined (zeros) for the W1 GEMM
#pragma unroll
        for (int t = 0; t < 6; ++t) xn[n * DD + t * 256 + threadIdx.x] = 0.f;
        return;
    }
    float v[6];
#pragma unroll
    for (int t = 0; t < 6; ++t) {
        int d = t * 256 + threadIdx.x;
        float s = b_agg[d];
#pragma unroll
        for (int ss = 0; ss < 8; ++ss) s += Cpart[ss * (NFR * DD) + n * DD + d];
        v[t] = s;
    }
    float local = v[0] + v[1] + v[2] + v[3] + v[4] + v[5];
    float mu = blockSum(local, sb) * (1.0f / (float)DD);
    float ls = 0.f;
#pragma unroll
    for (int t = 0; t < 6; ++t) { float dd = v[t] - mu; ls += dd * dd; }
    float var = blockSum(ls, sb) * (1.0f / (float)DD);
    float rstd = rsqrtf(var + 1e-5f);
#pragma unroll
    for (int t = 0; t < 6; ++t) {
        int d = t * 256 + threadIdx.x;
        xn[n * DD + d] = (v[t] - mu) * rstd * ln_g[d] + ln_b[d];
    }
}

// ---------------- K6 (fused k5b+k6): reduce partials + b1, GELU, gate logits, gumbel y ----------------
// Identical arithmetic sequence to the previous k5b -> k6 pair (h values and dot order unchanged).
__global__ __launch_bounds__(256) void k6_gate(const float* __restrict__ Cpart,
                                               const float* __restrict__ b1,
                                               const float* __restrict__ W2,
                                               const float* __restrict__ b2,
                                               const float* __restrict__ u,
                                               float* __restrict__ outGate,
                                               float* __restrict__ y) {
    __shared__ float sb[4];
    const int n = blockIdx.x;
    float a0 = 0.f, a1 = 0.f;
#pragma unroll
    for (int t = 0; t < 6; ++t) {
        int d = t * 256 + threadIdx.x;
        float s = b1[d];
#pragma unroll
        for (int ss = 0; ss < 8; ++ss) s += Cpart[ss * (NFR * DD) + n * DD + d];
        float hv = 0.5f * s * (1.0f + erff(s * 0.70710678118654752f));  // exact GELU
        a0 += hv * W2[2 * d];
        a1 += hv * W2[2 * d + 1];
    }
    a0 = blockSum(a0, sb);
    a1 = blockSum(a1, sb);
    if (threadIdx.x == 0) {
        float gl0 = a0 + b2[0], gl1 = a1 + b2[1];
        outGate[2 * n]     = gl0;
        outGate[2 * n + 1] = gl1;
        float g0 = -logf(-logf(u[2 * n]     + 1e-20f) + 1e-20f);
        float g1 = -logf(-logf(u[2 * n + 1] + 1e-20f) + 1e-20f);
        float s0 = (gl0 + g0 * 0.1f) * 2.0f;   // /TEMP, TEMP=0.5
        float s1 = (gl1 + g1 * 0.1f) * 2.0f;
        float m = fmaxf(s0, s1);
        float e0 = expf(s0 - m), e1 = expf(s1 - m);
        y[n] = e1 / (e0 + e1);
    }
}

// ---------------- K7: parallel top-8 selection (128 threads, 8 argmax rounds) ----------------
// Tie-break: equal value -> lowest index (matches jax.lax.top_k). Same selected set as the
// previous serial version; z_hard forward value is exactly y_hard in fp32 (Sterbenz).
__global__ __launch_bounds__(128) void k7_topk(const float* __restrict__ y,
                                               int* __restrict__ selFrames,
                                               float* __restrict__ outZ) {
    __shared__ float vals[128];
    __shared__ int   taken[128];
    __shared__ float wv[2];
    __shared__ int   wi[2];
    const int t = threadIdx.x;
    vals[t]  = (t < 127) ? y[t] : -1e30f;
    taken[t] = 0;
    __syncthreads();
    for (int c = 0; c < NCUBES; ++c) {
        float v = taken[t] ? -1e30f : vals[t];
        int   i = t;
#pragma unroll
        for (int o = 32; o > 0; o >>= 1) {
            float ov = __shfl_down(v, o);
            int   oi = __shfl_down(i, o);
            if (ov > v || (ov == v && oi < i)) { v = ov; i = oi; }
        }
        if ((t & 63) == 0) { wv[t >> 6] = v; wi[t >> 6] = i; }
        __syncthreads();
        if (t == 0) {
            int win = (wv[1] > wv[0] || (wv[1] == wv[0] && wi[1] < wi[0])) ? wi[1] : wi[0];
            taken[win] = 1;
            selFrames[c + 1] = win + 1;
        }
        __syncthreads();
    }
    if (t == 0) { selFrames[0] = 0; outZ[0] = 1.0f; }
    if (t < 127) outZ[1 + t] = taken[t] ? 1.0f : 0.0f;
}

// ---------------- K8: selected-frame pooled partials ----------------
__global__ __launch_bounds__(384) void k8_pool(const float* __restrict__ vf,
                                               const int* __restrict__ selFrames,
                                               float* __restrict__ pPart) {
    const int q = blockIdx.x, slot = blockIdx.y, c4 = threadIdx.x;
    const int n = selFrames[slot];
    const float4* v = (const float4*)vf;
    float4 acc = make_float4(0.f, 0.f, 0.f, 0.f);
    int base = (n * PP + q * PQ) * D4 + c4;
#pragma unroll
    for (int r = 0; r < PQ; ++r) {
        float4 x = v[base + r * D4];
        acc.x += x.x; acc.y += x.y; acc.z += x.z; acc.w += x.w;
    }
    ((float4*)pPart)[(slot * NQQ + q) * D4 + c4] = acc;
}

// ---------------- K8b: reduce pooled partials (x 1/81) ----------------
__global__ __launch_bounds__(256) void k8b_pool(const float* __restrict__ pPart,
                                                float* __restrict__ pooled) {
    const int q = blockIdx.x;
    const int d = blockIdx.y * 256 + threadIdx.x;
    float s = 0.f;
#pragma unroll
    for (int slot = 0; slot < NSEL; ++slot) s += pPart[(slot * NQQ + q) * DD + d];
    pooled[q * DD + d] = s * (1.0f / 81.0f);   // / z.sum()=9 and / 9 patches
}

// ---------------- K10: reduce thumbnail partials (4 splits) + b_th ----------------
__global__ __launch_bounds__(256) void k10_thumb(const float* __restrict__ Cpart,
                                                 const float* __restrict__ b_th,
                                                 float* __restrict__ outT) {
    const int q = blockIdx.x;
    const int l = blockIdx.y * 256 + threadIdx.x;
    float s = b_th[l];
#pragma unroll
    for (int ss = 0; ss < 4; ++ss) s += Cpart[ss * (NQQ * LMM) + q * LMM + l];
    outT[q * LMM + l] = s;
}

extern "C" void kernel_launch(void* const* d_in, const int* in_sizes, int n_in,
                              void* d_out, int out_size, void* d_ws, size_t ws_size,
                              hipStream_t stream) {
    // Inputs are fp32 (reference dtypes); output fp32.
    const float* vf    = (const float*)d_in[0];
    const float* u     = (const float*)d_in[1];
    const float* W_agg = (const float*)d_in[2];
    const float* b_agg = (const float*)d_in[3];
    const float* ln_g  = (const float*)d_in[4];
    const float* ln_b  = (const float*)d_in[5];
    const float* W1    = (const float*)d_in[6];
    const float* b1    = (const float*)d_in[7];
    const float* W2    = (const float*)d_in[8];
    const float* b2    = (const float*)d_in[9];
    const float* W_th  = (const float*)d_in[10];
    const float* b_th  = (const float*)d_in[11];

    float* ws = (float*)d_ws;
    float* regA    = ws + OFF_A;       // part, later Cpart
    float* momMean = ws + OFF_MOM;
    float* xn      = ws + OFF_XN;
    float* pPart   = ws + OFF_PPART;
    float* pooled  = ws + OFF_POOLED;
    float* yv      = ws + OFF_Y;
    int*   sel     = (int*)(ws + OFF_SEL);

    float* out = (float*)d_out;
    float* outGate  = out + OUT_GATE;
    float* outThumb = out + OUT_THUMB;
    float* outZ     = out + OUT_Z;

    // Step 1+2 collapsed: patch-sum partials, fused mean+EMA scan, small GEMM
    k1_partial<<<dim3(NFR, 8), 384, 0, stream>>>(vf, regA);
    k2_scan<<<24, 64, 0, stream>>>(regA, momMean);
    // feat_raw = momMean @ W_agg (8-way split-K partials into regA)
    gemm_sk<<<dim3(24, 2, 8), 256, 0, stream>>>(momMean, W_agg, regA, NFR, DD, DD, 192);
    k4_ln<<<NFR, 256, 0, stream>>>(regA, b_agg, ln_g, ln_b, xn);
    // h_raw = xn @ W1
    gemm_sk<<<dim3(24, 2, 8), 256, 0, stream>>>(xn, W1, regA, NFR, DD, DD, 192);
    k6_gate<<<127, 256, 0, stream>>>(regA, b1, W2, b2, u, outGate, yv);
    k7_topk<<<1, 128, 0, stream>>>(yv, sel, outZ);
    k8_pool<<<dim3(NQQ, NSEL), 384, 0, stream>>>(vf, sel, pPart);
    k8b_pool<<<dim3(NQQ, 6), 256, 0, stream>>>(pPart, pooled);
    // thumb_raw = pooled @ W_th (4-way split-K into regA)
    gemm_sk<<<dim3(64, 1, 4), 256, 0, stream>>>(pooled, W_th, regA, NQQ, LMM, DD, 384);
    k10_thumb<<<dim3(NQQ, 16), 256, 0, stream>>>(regA, b_th, outThumb);
}